// Round 1
// baseline (3465.779 us; speedup 1.0000x reference)
//
#include <hip/hip_runtime.h>

#define HDIM 64
#define IN_DIM 4
#define BATCH 256
#define TLEN 2048
#define CH 16   // layer-2 streaming chunk (steps)

__device__ __forceinline__ float sigmoid_fast(float x) {
    return 1.0f / (1.0f + __expf(-x));
}
__device__ __forceinline__ float tanh_fast(float x) {
    // tanh(x) = 1 - 2/(exp(2x)+1); stable at both extremes
    return 1.0f - 2.0f / (__expf(2.0f * x) + 1.0f);
}

// ---------------- Layer 1: bidirectional, input dim 4 ----------------
// grid = 2*BATCH blocks (batch, direction), 256 threads.
// quad (tid>>2) owns hidden unit u; lane p=tid&3 owns k-slice of 16.
__global__ __launch_bounds__(256, 2)
void lstm_layer1(const float* __restrict__ x,      // [B,T,4]
                 const float* __restrict__ Wih_f, const float* __restrict__ Whh_f, const float* __restrict__ b_f,
                 const float* __restrict__ Wih_b, const float* __restrict__ Whh_b, const float* __restrict__ b_b,
                 float* __restrict__ out1)         // [B,T,2H]
{
    const int bidx = blockIdx.x >> 1;
    const int dir  = blockIdx.x & 1;
    const float* __restrict__ Wih = dir ? Wih_b : Wih_f;
    const float* __restrict__ Whh = dir ? Whh_b : Whh_f;
    const float* __restrict__ bb  = dir ? b_b   : b_f;

    const int tid = threadIdx.x;
    const int w   = tid >> 6;        // wave 0..3
    const int qw  = (tid & 63) >> 2; // quad in wave
    const int p   = tid & 3;         // k-slice
    const int u   = w * 16 + qw;     // hidden unit 0..63

    __shared__ float xlds[TLEN * IN_DIM];   // 32 KB
    __shared__ float hbuf[2][HDIM];

    // preload x[b] (T*IN = 8192 floats = 2048 float4)
    {
        const float4* src = (const float4*)(x + (size_t)bidx * TLEN * IN_DIM);
        float4* dst = (float4*)xlds;
        #pragma unroll
        for (int i = 0; i < (TLEN * IN_DIM / 4) / 256; ++i)
            dst[tid + 256 * i] = src[tid + 256 * i];
    }
    if (tid < HDIM) { hbuf[0][tid] = 0.f; hbuf[1][tid] = 0.f; }

    // weights: gates gi in {i,f,g,o}; row = gi*64+u; k-slice 16p..16p+15
    float4 whh[4][4];
    float4 wih[4];
    float  bias[4];
    #pragma unroll
    for (int gi = 0; gi < 4; ++gi) {
        const float* row = Whh + (size_t)(gi * 64 + u) * HDIM + 16 * p;
        #pragma unroll
        for (int i = 0; i < 4; ++i) whh[gi][i] = ((const float4*)row)[i];
        wih[gi]  = ((const float4*)(Wih + (size_t)(gi * 64 + u) * IN_DIM))[0];
        bias[gi] = bb[gi * 64 + u];
    }
    __syncthreads();

    float c = 0.f;
    float* outbase = out1 + (size_t)bidx * TLEN * (2 * HDIM) + dir * HDIM + u;

    for (int s = 0; s < TLEN; ++s) {
        const int t  = dir ? (TLEN - 1 - s) : s;
        const int rb = s & 1;

        float4 hc[4];
        #pragma unroll
        for (int i = 0; i < 4; ++i)
            hc[i] = ((const float4*)(&hbuf[rb][16 * p]))[i];

        float g[4];
        #pragma unroll
        for (int gi = 0; gi < 4; ++gi) {
            float acc = 0.f;
            #pragma unroll
            for (int i = 0; i < 4; ++i) {
                acc += whh[gi][i].x * hc[i].x;
                acc += whh[gi][i].y * hc[i].y;
                acc += whh[gi][i].z * hc[i].z;
                acc += whh[gi][i].w * hc[i].w;
            }
            g[gi] = acc;
        }
        // quad butterfly: sum the 4 k-slices
        #pragma unroll
        for (int gi = 0; gi < 4; ++gi) {
            g[gi] += __shfl_xor(g[gi], 1, 64);
            g[gi] += __shfl_xor(g[gi], 2, 64);
        }
        // bias + x projection (redundant per quad, consistent)
        const float4 xv = ((const float4*)(xlds + t * IN_DIM))[0];
        #pragma unroll
        for (int gi = 0; gi < 4; ++gi)
            g[gi] += bias[gi] + xv.x * wih[gi].x + xv.y * wih[gi].y
                              + xv.z * wih[gi].z + xv.w * wih[gi].w;

        const float ig = sigmoid_fast(g[0]);
        const float fg = sigmoid_fast(g[1]);
        const float gg = tanh_fast(g[2]);
        const float og = sigmoid_fast(g[3]);
        c = fg * c + ig * gg;
        const float h = og * tanh_fast(c);

        if (p == 0) {
            hbuf[rb ^ 1][u] = h;
            outbase[(size_t)t * (2 * HDIM)] = h;
        }
        __syncthreads();
    }
}

// ---------------- Layer 2: unidirectional, input dim 128, + FC ----------------
// grid = BATCH blocks, 256 threads. Lane p owns 16 of 64 (recurrent) and 32 of 128 (input).
__global__ __launch_bounds__(256, 1)
void lstm_layer2(const float* __restrict__ out1,  // [B,T,128]
                 const float* __restrict__ Wih2, const float* __restrict__ Whh2, const float* __restrict__ b2,
                 const float* __restrict__ Wfc, const float* __restrict__ bfc,
                 float* __restrict__ out)         // [B,1]
{
    const int bidx = blockIdx.x;
    const int tid  = threadIdx.x;
    const int w    = tid >> 6;
    const int lw   = tid & 63;
    const int qw   = lw >> 2;
    const int p    = tid & 3;
    const int u    = w * 16 + qw;

    __shared__ float inbuf[2][CH][2 * HDIM];  // 16 KB
    __shared__ float hbuf[2][HDIM];

    float4 whh[4][4];
    float4 win[4][8];
    float  bias[4];
    #pragma unroll
    for (int gi = 0; gi < 4; ++gi) {
        const float* row = Whh2 + (size_t)(gi * 64 + u) * HDIM + 16 * p;
        #pragma unroll
        for (int i = 0; i < 4; ++i) whh[gi][i] = ((const float4*)row)[i];
        const float* row2 = Wih2 + (size_t)(gi * 64 + u) * (2 * HDIM);
        // rotated-by-p load order, matching the LDS read rotation (bank-conflict-free)
        #pragma unroll
        for (int j = 0; j < 8; ++j) {
            const int off = 32 * p + (((j + 2 * p) & 7) << 2);
            win[gi][j] = *(const float4*)(row2 + off);
        }
        bias[gi] = b2[gi * 64 + u];
    }
    if (tid < HDIM) { hbuf[0][tid] = 0.f; hbuf[1][tid] = 0.f; }

    const float4* src = (const float4*)(out1 + (size_t)bidx * TLEN * (2 * HDIM));
    // preload chunk 0: CH*128 floats = 512 float4
    {
        float4* dst = (float4*)&inbuf[0][0][0];
        dst[tid]       = src[tid];
        dst[tid + 256] = src[tid + 256];
    }
    __syncthreads();

    float c = 0.f;

    for (int chunk = 0; chunk < TLEN / CH; ++chunk) {
        const int cb = chunk & 1;
        const int nc = chunk + 1;
        const bool havenext = (nc < TLEN / CH);
        float4 pf0, pf1;
        if (havenext) {
            const float4* s2 = src + (size_t)nc * (CH * 32);
            pf0 = s2[tid];
            pf1 = s2[tid + 256];
        }
        #pragma unroll 1
        for (int ts = 0; ts < CH; ++ts) {
            const int s  = chunk * CH + ts;
            const int rb = s & 1;

            float4 hc[4];
            #pragma unroll
            for (int i = 0; i < 4; ++i)
                hc[i] = ((const float4*)(&hbuf[rb][16 * p]))[i];

            const float* xin = &inbuf[cb][ts][0];
            float4 xc[8];
            #pragma unroll
            for (int j = 0; j < 8; ++j) {
                const int off = 32 * p + (((j + 2 * p) & 7) << 2);
                xc[j] = *(const float4*)(xin + off);
            }

            float g[4];
            #pragma unroll
            for (int gi = 0; gi < 4; ++gi) {
                float acc = 0.f;
                #pragma unroll
                for (int i = 0; i < 4; ++i) {
                    acc += whh[gi][i].x * hc[i].x;
                    acc += whh[gi][i].y * hc[i].y;
                    acc += whh[gi][i].z * hc[i].z;
                    acc += whh[gi][i].w * hc[i].w;
                }
                #pragma unroll
                for (int j = 0; j < 8; ++j) {
                    acc += win[gi][j].x * xc[j].x;
                    acc += win[gi][j].y * xc[j].y;
                    acc += win[gi][j].z * xc[j].z;
                    acc += win[gi][j].w * xc[j].w;
                }
                g[gi] = acc;
            }
            #pragma unroll
            for (int gi = 0; gi < 4; ++gi) {
                g[gi] += __shfl_xor(g[gi], 1, 64);
                g[gi] += __shfl_xor(g[gi], 2, 64);
                g[gi] += bias[gi];
            }

            const float ig = sigmoid_fast(g[0]);
            const float fg = sigmoid_fast(g[1]);
            const float gg = tanh_fast(g[2]);
            const float og = sigmoid_fast(g[3]);
            c = fg * c + ig * gg;
            const float h = og * tanh_fast(c);

            if (p == 0) hbuf[rb ^ 1][u] = h;
            __syncthreads();
        }
        if (havenext) {
            float4* dst = (float4*)&inbuf[cb ^ 1][0][0];
            dst[tid]       = pf0;
            dst[tid + 256] = pf1;
            __syncthreads();
        }
    }

    // T even -> final h lives in hbuf[0]. FC: out[b] = dot(h, Wfc) + bfc
    if (w == 0) {
        float part = hbuf[0][lw] * Wfc[lw];
        #pragma unroll
        for (int m = 1; m < 64; m <<= 1)
            part += __shfl_xor(part, m, 64);
        if (lw == 0) out[bidx] = part + bfc[0];
    }
}

extern "C" void kernel_launch(void* const* d_in, const int* in_sizes, int n_in,
                              void* d_out, int out_size, void* d_ws, size_t ws_size,
                              hipStream_t stream) {
    const float* x     = (const float*)d_in[0];
    const float* Wih_f = (const float*)d_in[1];
    const float* Whh_f = (const float*)d_in[2];
    const float* b_f   = (const float*)d_in[3];
    const float* Wih_b = (const float*)d_in[4];
    const float* Whh_b = (const float*)d_in[5];
    const float* b_b   = (const float*)d_in[6];
    const float* Wih2  = (const float*)d_in[7];
    const float* Whh2  = (const float*)d_in[8];
    const float* b2    = (const float*)d_in[9];
    const float* Wfc   = (const float*)d_in[10];
    const float* bfc   = (const float*)d_in[11];

    float* out1 = (float*)d_ws;  // [B,T,2H] fp32 = 256 MiB of workspace

    lstm_layer1<<<dim3(2 * BATCH), dim3(256), 0, stream>>>(
        x, Wih_f, Whh_f, b_f, Wih_b, Whh_b, b_b, out1);
    lstm_layer2<<<dim3(BATCH), dim3(256), 0, stream>>>(
        out1, Wih2, Whh2, b2, Wfc, bfc, (float*)d_out);
}

// Round 2
// 2214.937 us; speedup vs baseline: 1.5647x; 1.5647x over previous
//
#include <hip/hip_runtime.h>

#define HDIM 64
#define BATCH 256
#define TLEN 2048
#define CH 16   // layer-2 streaming chunk (steps)

__device__ __forceinline__ float rcp_fast(float x) { return __builtin_amdgcn_rcpf(x); }
__device__ __forceinline__ float sigmoid_fast(float x) { return rcp_fast(1.0f + __expf(-x)); }
__device__ __forceinline__ float tanh_fast(float x)    { return 1.0f - 2.0f * rcp_fast(1.0f + __expf(2.0f * x)); }

// quad_perm DPP adds: lane^1 and lane^2 (VALU, no LDS pipe)
__device__ __forceinline__ float dpp_xor1_add(float x) {
    int v = __builtin_amdgcn_update_dpp(0, __float_as_int(x), 0xB1, 0xF, 0xF, true);
    return x + __int_as_float(v);
}
__device__ __forceinline__ float dpp_xor2_add(float x) {
    int v = __builtin_amdgcn_update_dpp(0, __float_as_int(x), 0x4E, 0xF, 0xF, true);
    return x + __int_as_float(v);
}
__device__ __forceinline__ float swz_xor4_add(float x) {
    int v = __builtin_amdgcn_ds_swizzle(__float_as_int(x), 0x101F); // xor-4 butterfly
    return x + __int_as_float(v);
}
__device__ __forceinline__ float dot4(float4 a, float4 b, float acc) {
    acc = fmaf(a.x, b.x, acc); acc = fmaf(a.y, b.y, acc);
    acc = fmaf(a.z, b.z, acc); acc = fmaf(a.w, b.w, acc);
    return acc;
}

// ---------------- Layer 1: bidirectional, input dim 4 ----------------
// grid = 2*BATCH blocks, 256 threads. Quad owns unit u = tid>>2; lane p = tid&3
// owns k-slice of 16. Weights in named registers (64 VGPR), quad-DPP reduce.
__global__ __launch_bounds__(256, 2)
void lstm_layer1(const float* __restrict__ x,      // [B,T,4]
                 const float* __restrict__ Wih_f, const float* __restrict__ Whh_f, const float* __restrict__ b_f,
                 const float* __restrict__ Wih_b, const float* __restrict__ Whh_b, const float* __restrict__ b_b,
                 float* __restrict__ out1)         // [B,T,2H]
{
    const int bidx = blockIdx.x >> 1;
    const int dir  = blockIdx.x & 1;
    const float* __restrict__ Wih = dir ? Wih_b : Wih_f;
    const float* __restrict__ Whh = dir ? Whh_b : Whh_f;
    const float* __restrict__ bb  = dir ? b_b   : b_f;

    const int tid = threadIdx.x;
    const int u   = tid >> 2;
    const int p   = tid & 3;

    __shared__ float xlds[TLEN * 4];    // 32 KB
    __shared__ float hbuf[2][HDIM];

    {   // preload x[b] (2048 float4)
        const float4* src = (const float4*)(x + (size_t)bidx * TLEN * 4);
        float4* dst = (float4*)xlds;
        #pragma unroll
        for (int i = 0; i < 8; ++i) dst[tid + 256 * i] = src[tid + 256 * i];
    }
    if (tid < 2 * HDIM) ((float*)hbuf)[tid] = 0.f;

    // recurrent weights: row gi*64+u, cols [16p,16p+16)
    const float* wbase = Whh + (size_t)u * HDIM + 16 * p;
    const float4 W00 = *(const float4*)(wbase + 0*4096 +  0), W01 = *(const float4*)(wbase + 0*4096 +  4),
                 W02 = *(const float4*)(wbase + 0*4096 +  8), W03 = *(const float4*)(wbase + 0*4096 + 12);
    const float4 W10 = *(const float4*)(wbase + 1*4096 +  0), W11 = *(const float4*)(wbase + 1*4096 +  4),
                 W12 = *(const float4*)(wbase + 1*4096 +  8), W13 = *(const float4*)(wbase + 1*4096 + 12);
    const float4 W20 = *(const float4*)(wbase + 2*4096 +  0), W21 = *(const float4*)(wbase + 2*4096 +  4),
                 W22 = *(const float4*)(wbase + 2*4096 +  8), W23 = *(const float4*)(wbase + 2*4096 + 12);
    const float4 W30 = *(const float4*)(wbase + 3*4096 +  0), W31 = *(const float4*)(wbase + 3*4096 +  4),
                 W32 = *(const float4*)(wbase + 3*4096 +  8), W33 = *(const float4*)(wbase + 3*4096 + 12);
    const float4 I0 = *(const float4*)(Wih + (0*64 + u) * 4);
    const float4 I1 = *(const float4*)(Wih + (1*64 + u) * 4);
    const float4 I2 = *(const float4*)(Wih + (2*64 + u) * 4);
    const float4 I3 = *(const float4*)(Wih + (3*64 + u) * 4);
    const float b0 = bb[u], b1 = bb[64 + u], b2g = bb[128 + u], b3 = bb[192 + u];
    __syncthreads();

    float c = 0.f;
    const float* xp = xlds + (dir ? (TLEN - 1) * 4 : 0);
    const int xstep = dir ? -4 : 4;
    float* outp = out1 + (size_t)bidx * TLEN * (2 * HDIM)
                + (size_t)(dir ? (TLEN - 1) : 0) * (2 * HDIM) + dir * HDIM + u;
    const ptrdiff_t ostep = dir ? -(2 * HDIM) : (2 * HDIM);

    #pragma unroll 2
    for (int s = 0; s < TLEN; ++s) {
        const float* hb = hbuf[s & 1];
        const float4 h0 = *(const float4*)(hb + 16 * p + 0);
        const float4 h1 = *(const float4*)(hb + 16 * p + 4);
        const float4 h2 = *(const float4*)(hb + 16 * p + 8);
        const float4 h3 = *(const float4*)(hb + 16 * p + 12);

        float g0 = dot4(W03, h3, dot4(W02, h2, dot4(W01, h1, dot4(W00, h0, 0.f))));
        float g1 = dot4(W13, h3, dot4(W12, h2, dot4(W11, h1, dot4(W10, h0, 0.f))));
        float g2 = dot4(W23, h3, dot4(W22, h2, dot4(W21, h1, dot4(W20, h0, 0.f))));
        float g3 = dot4(W33, h3, dot4(W32, h2, dot4(W31, h1, dot4(W30, h0, 0.f))));

        g0 = dpp_xor2_add(dpp_xor1_add(g0));
        g1 = dpp_xor2_add(dpp_xor1_add(g1));
        g2 = dpp_xor2_add(dpp_xor1_add(g2));
        g3 = dpp_xor2_add(dpp_xor1_add(g3));

        const float4 xv = *(const float4*)xp;
        g0 += dot4(I0, xv, b0);
        g1 += dot4(I1, xv, b1);
        g2 += dot4(I2, xv, b2g);
        g3 += dot4(I3, xv, b3);

        const float ig = sigmoid_fast(g0);
        const float fg = sigmoid_fast(g1);
        const float gg = tanh_fast(g2);
        const float og = sigmoid_fast(g3);
        c = fmaf(fg, c, ig * gg);
        const float h = og * tanh_fast(c);

        if (p == 0) {
            hbuf[(s & 1) ^ 1][u] = h;
            *outp = h;
        }
        outp += ostep;
        xp   += xstep;
        __syncthreads();
    }
}

// ---------------- Layer 2: unidirectional, input dim 128, + FC ----------------
// grid = BATCH blocks, 512 threads (8 waves). Lane = (u-group, p8): unit
// u = (tid>>6)*8 + ((tid&63)>>3), slice p8 = tid&7 owns k-slices 8 (recurrent)
// and 16 (input). Reduce: DPP xor1/xor2 + ds_swizzle xor4.
__global__ __launch_bounds__(512, 2)
void lstm_layer2(const float* __restrict__ out1,  // [B,T,128]
                 const float* __restrict__ Wih2, const float* __restrict__ Whh2, const float* __restrict__ bias2,
                 const float* __restrict__ Wfc, const float* __restrict__ bfc,
                 float* __restrict__ out)         // [B,1]
{
    const int bidx = blockIdx.x;
    const int tid  = threadIdx.x;
    const int w    = tid >> 6;
    const int lane = tid & 63;
    const int ul   = lane >> 3;
    const int p8   = lane & 7;
    const int u    = w * 8 + ul;
    const int rot  = p8 >> 1;   // bank-conflict-avoiding read rotation

    __shared__ float inbuf[2][CH][2 * HDIM];  // 16 KB
    __shared__ float hbuf[2][HDIM];

    // recurrent weights: row gi*64+u, cols [8p8, 8p8+8)
    const float* whbase = Whh2 + (size_t)u * HDIM + 8 * p8;
    const float4 H00 = *(const float4*)(whbase + 0*4096 + 0), H01 = *(const float4*)(whbase + 0*4096 + 4);
    const float4 H10 = *(const float4*)(whbase + 1*4096 + 0), H11 = *(const float4*)(whbase + 1*4096 + 4);
    const float4 H20 = *(const float4*)(whbase + 2*4096 + 0), H21 = *(const float4*)(whbase + 2*4096 + 4);
    const float4 H30 = *(const float4*)(whbase + 3*4096 + 0), H31 = *(const float4*)(whbase + 3*4096 + 4);
    // input weights: row gi*64+u, cols 16p8 + 4*((j+rot)&3), j=0..3
    const float* wibase = Wih2 + (size_t)u * 128 + 16 * p8;
    #define LWI(g, j) *(const float4*)(wibase + (g)*8192 + ((((j) + rot) & 3) << 2))
    const float4 X00 = LWI(0,0), X01 = LWI(0,1), X02 = LWI(0,2), X03 = LWI(0,3);
    const float4 X10 = LWI(1,0), X11 = LWI(1,1), X12 = LWI(1,2), X13 = LWI(1,3);
    const float4 X20 = LWI(2,0), X21 = LWI(2,1), X22 = LWI(2,2), X23 = LWI(2,3);
    const float4 X30 = LWI(3,0), X31 = LWI(3,1), X32 = LWI(3,2), X33 = LWI(3,3);
    #undef LWI
    const float b0 = bias2[u], b1 = bias2[64 + u], b2g = bias2[128 + u], b3 = bias2[192 + u];

    if (tid < 2 * HDIM) ((float*)hbuf)[tid] = 0.f;

    const float4* src = (const float4*)(out1 + (size_t)bidx * TLEN * (2 * HDIM));
    ((float4*)&inbuf[0][0][0])[tid] = src[tid];   // chunk 0: 512 float4
    __syncthreads();

    float c = 0.f;

    for (int chunk = 0; chunk < TLEN / CH; ++chunk) {
        const int cb = chunk & 1;
        const bool havenext = (chunk + 1 < TLEN / CH);
        float4 pf;
        if (havenext) pf = src[(size_t)(chunk + 1) * 512 + tid];

        #pragma unroll 2
        for (int ts = 0; ts < CH; ++ts) {
            const int s = chunk * CH + ts;
            const float* hb = hbuf[s & 1];
            const float* xr = &inbuf[cb][ts][16 * p8];

            const float4 x0 = *(const float4*)(xr + (((0 + rot) & 3) << 2));
            const float4 x1 = *(const float4*)(xr + (((1 + rot) & 3) << 2));
            const float4 x2 = *(const float4*)(xr + (((2 + rot) & 3) << 2));
            const float4 x3 = *(const float4*)(xr + (((3 + rot) & 3) << 2));
            const float4 h0 = *(const float4*)(hb + 8 * p8 + 0);
            const float4 h1 = *(const float4*)(hb + 8 * p8 + 4);

            float g0 = dot4(H01, h1, dot4(H00, h0, dot4(X03, x3, dot4(X02, x2, dot4(X01, x1, dot4(X00, x0, 0.f))))));
            float g1 = dot4(H11, h1, dot4(H10, h0, dot4(X13, x3, dot4(X12, x2, dot4(X11, x1, dot4(X10, x0, 0.f))))));
            float g2 = dot4(H21, h1, dot4(H20, h0, dot4(X23, x3, dot4(X22, x2, dot4(X21, x1, dot4(X20, x0, 0.f))))));
            float g3 = dot4(H31, h1, dot4(H30, h0, dot4(X33, x3, dot4(X32, x2, dot4(X31, x1, dot4(X30, x0, 0.f))))));

            g0 = swz_xor4_add(dpp_xor2_add(dpp_xor1_add(g0))) + b0;
            g1 = swz_xor4_add(dpp_xor2_add(dpp_xor1_add(g1))) + b1;
            g2 = swz_xor4_add(dpp_xor2_add(dpp_xor1_add(g2))) + b2g;
            g3 = swz_xor4_add(dpp_xor2_add(dpp_xor1_add(g3))) + b3;

            const float ig = sigmoid_fast(g0);
            const float fg = sigmoid_fast(g1);
            const float gg = tanh_fast(g2);
            const float og = sigmoid_fast(g3);
            c = fmaf(fg, c, ig * gg);
            const float h = og * tanh_fast(c);

            if (p8 == 0) hbuf[(s & 1) ^ 1][u] = h;
            __syncthreads();
        }
        if (havenext) {
            ((float4*)&inbuf[cb ^ 1][0][0])[tid] = pf;
            __syncthreads();
        }
    }

    // final h (T even) is in hbuf[0]; FC
    if (w == 0) {
        float part = hbuf[0][lane] * Wfc[lane];
        #pragma unroll
        for (int m = 1; m < 64; m <<= 1) part += __shfl_xor(part, m, 64);
        if (lane == 0) out[bidx] = part + bfc[0];
    }
}

extern "C" void kernel_launch(void* const* d_in, const int* in_sizes, int n_in,
                              void* d_out, int out_size, void* d_ws, size_t ws_size,
                              hipStream_t stream) {
    const float* x     = (const float*)d_in[0];
    const float* Wih_f = (const float*)d_in[1];
    const float* Whh_f = (const float*)d_in[2];
    const float* b_f   = (const float*)d_in[3];
    const float* Wih_b = (const float*)d_in[4];
    const float* Whh_b = (const float*)d_in[5];
    const float* b_b   = (const float*)d_in[6];
    const float* Wih2  = (const float*)d_in[7];
    const float* Whh2  = (const float*)d_in[8];
    const float* b2    = (const float*)d_in[9];
    const float* Wfc   = (const float*)d_in[10];
    const float* bfc   = (const float*)d_in[11];

    float* out1 = (float*)d_ws;  // [B,T,2H] fp32 (256 MiB workspace)

    lstm_layer1<<<dim3(2 * BATCH), dim3(256), 0, stream>>>(
        x, Wih_f, Whh_f, b_f, Wih_b, Whh_b, b_b, out1);
    lstm_layer2<<<dim3(BATCH), dim3(512), 0, stream>>>(
        out1, Wih2, Whh2, b2, Wfc, bfc, (float*)d_out);
}